// Round 1
// baseline (275.017 us; speedup 1.0000x reference)
//
#include <hip/hip_runtime.h>
#include <stdint.h>

#define N_OUT_  4096
#define N_IN_   4096
#define BATCH_  4096
#define NNZ_    1600000

typedef unsigned short ushort_t;
typedef float  f32x4  __attribute__((ext_vector_type(4)));
typedef short  short8 __attribute__((ext_vector_type(8)));
typedef __bf16 bf16x8 __attribute__((ext_vector_type(8)));

// RNE f32 -> bf16 (bit-level, matches HW conversion)
__device__ inline ushort_t f32_to_bf16(float f) {
  uint32_t u = __float_as_uint(f);
  uint32_t r = u + 0x7FFFu + ((u >> 16) & 1u);
  return (ushort_t)(r >> 16);
}

// async global->LDS, 16B per lane. LDS dest must be wave-uniform base; HW
// writes base + lane*16 (linear). Guide: measured working on gfx950 (m97).
__device__ inline void gload_lds16(const void* g, void* l) {
  __builtin_amdgcn_global_load_lds(
      (const __attribute__((address_space(1))) void*)g,
      (__attribute__((address_space(3))) void*)l,
      16, 0, 0);
}

__device__ inline f32x4 mfma_bf16(short8 a, short8 b, f32x4 c) {
  return __builtin_amdgcn_mfma_f32_16x16x32_bf16(
      __builtin_bit_cast(bf16x8, a), __builtin_bit_cast(bf16x8, b), c, 0, 0, 0);
}

// ---------------- 1. COO scatter-add into dense f32 W ----------------
__global__ __launch_bounds__(256) void scatter_coo(
    const float* __restrict__ vals, const int* __restrict__ rows,
    const int* __restrict__ cols, float* __restrict__ W) {
  int i = blockIdx.x * 256 + threadIdx.x;
  if (i < NNZ_) {
    atomicAdd(&W[(size_t)rows[i] * N_IN_ + cols[i]], vals[i]);
  }
}

// ---------------- 2. W f32 -> bf16 (element-wise, vectorized) ----------------
__global__ __launch_bounds__(256) void convert_w(
    const float* __restrict__ Wf, ushort_t* __restrict__ Wb) {
  size_t i = ((size_t)blockIdx.x * 256 + threadIdx.x) * 4;
  float4 f = *(const float4*)(Wf + i);
  ushort4 u;
  u.x = f32_to_bf16(f.x);
  u.y = f32_to_bf16(f.y);
  u.z = f32_to_bf16(f.z);
  u.w = f32_to_bf16(f.w);
  *(ushort4*)(Wb + i) = u;
}

// ---------------- 3. inputs [K][N] f32 -> Bt [N][K] bf16 (tiled transpose) ----
__global__ __launch_bounds__(256) void transpose_bf16(
    const float* __restrict__ in, ushort_t* __restrict__ out) {
  __shared__ float tile[32][33];  // +1 pad: conflict-free both phases
  const int bx = blockIdx.x * 32;  // input col base (N / BATCH dim)
  const int by = blockIdx.y * 32;  // input row base (K / N_IN dim)
  const int tx = threadIdx.x;      // 0..31
  const int ty = threadIdx.y;      // 0..7
#pragma unroll
  for (int i = 0; i < 32; i += 8)
    tile[ty + i][tx] = in[(size_t)(by + ty + i) * BATCH_ + bx + tx];
  __syncthreads();
#pragma unroll
  for (int i = 0; i < 32; i += 8)
    out[(size_t)(bx + ty + i) * N_IN_ + by + tx] = f32_to_bf16(tile[tx][ty + i]);
}

// ---------------- 4. bf16 GEMM 128x128 tile + bias + relu (m97 structure) ----
// C[m][n] = relu( sum_k A[m][k] * Bt[n][k] + bias[m] )
__global__ __launch_bounds__(256, 2) void gemm_bias_relu(
    const ushort_t* __restrict__ A,    // W   bf16 [N_OUT][N_IN] row-major
    const ushort_t* __restrict__ Bt,   // in^T bf16 [BATCH][N_IN] row-major
    const float* __restrict__ bias,    // [N_OUT]
    float* __restrict__ C) {           // [N_OUT][BATCH] f32
  __shared__ __align__(16) ushort_t sA[128 * 32];  // [m 128][k 32]
  __shared__ __align__(16) ushort_t sB[128 * 32];  // [n 128][k 32]

  const int tid  = threadIdx.x;
  const int wave = tid >> 6;
  const int lane = tid & 63;

  const int brow = blockIdx.y * 128;
  const int bcol = blockIdx.x * 128;

  const int wm = wave >> 1;   // 0..1
  const int wn = wave & 1;    // 0..1

  // --- staging addressing: chunk c = wave*2+i writes LDS bytes [c*1024, +1024)
  // lane l covers LDS elems c*512 + l*8 -> tile row = c*16 + l/4, col = (l&3)*8
  const int srow0 = wave * 32 + (lane >> 2);
  const int scol  = (lane & 3) * 8;
  const size_t ga0 = (size_t)(brow + srow0) * N_IN_ + scol;
  const size_t ga1 = ga0 + (size_t)16 * N_IN_;
  const size_t gb0 = (size_t)(bcol + srow0) * N_IN_ + scol;
  const size_t gb1 = gb0 + (size_t)16 * N_IN_;
  ushort_t* ldsA0 = &sA[(wave * 2 + 0) * 512];
  ushort_t* ldsA1 = &sA[(wave * 2 + 1) * 512];
  ushort_t* ldsB0 = &sB[(wave * 2 + 0) * 512];
  ushort_t* ldsB1 = &sB[(wave * 2 + 1) * 512];

  // --- fragment addressing (16x16x32): row/col = lane&15, k0 = (lane>>4)*8
  const int fr = lane & 15;
  const int k0 = (lane >> 4) * 8;
  const int aBase = (wm * 64 + fr) * 32 + k0;
  const int bBase = (wn * 64 + fr) * 32 + k0;

  f32x4 acc[4][4] = {};

  for (int kt = 0; kt < N_IN_; kt += 32) {
    gload_lds16(A + ga0 + kt, ldsA0);
    gload_lds16(A + ga1 + kt, ldsA1);
    gload_lds16(Bt + gb0 + kt, ldsB0);
    gload_lds16(Bt + gb1 + kt, ldsB1);
    __syncthreads();  // compiler emits vmcnt(0) drain before s_barrier

    short8 av[4], bv[4];
#pragma unroll
    for (int i = 0; i < 4; ++i) {
      av[i] = *(const short8*)&sA[aBase + i * 16 * 32];
      bv[i] = *(const short8*)&sB[bBase + i * 16 * 32];
    }
#pragma unroll
    for (int mi = 0; mi < 4; ++mi)
#pragma unroll
      for (int ni = 0; ni < 4; ++ni)
        acc[mi][ni] = mfma_bf16(av[mi], bv[ni], acc[mi][ni]);

    __syncthreads();  // protect LDS before next stage
  }

  // --- epilogue: C/D layout col = lane&15, row = (lane>>4)*4 + reg
  const int r0 = wm * 64 + (lane >> 4) * 4;
  const int c0 = wn * 64 + fr;
#pragma unroll
  for (int mi = 0; mi < 4; ++mi) {
#pragma unroll
    for (int r = 0; r < 4; ++r) {
      const int row = brow + r0 + mi * 16 + r;
      const float b = bias[row];
#pragma unroll
      for (int ni = 0; ni < 4; ++ni) {
        float v = acc[mi][ni][r] + b;
        C[(size_t)row * BATCH_ + bcol + c0 + ni * 16] = v > 0.f ? v : 0.f;
      }
    }
  }
}

extern "C" void kernel_launch(void* const* d_in, const int* in_sizes, int n_in,
                              void* d_out, int out_size, void* d_ws, size_t ws_size,
                              hipStream_t stream) {
  const float* inputs = (const float*)d_in[0];  // [N_IN][BATCH] f32
  const float* values = (const float*)d_in[1];  // [NNZ] f32
  const float* biases = (const float*)d_in[2];  // [N_OUT] f32
  const int*   rows   = (const int*)d_in[3];    // [NNZ]
  const int*   cols   = (const int*)d_in[4];    // [NNZ]
  float* out = (float*)d_out;                   // [N_OUT][BATCH] f32

  // workspace layout: [0,64M) f32 W ; [64M,96M) bf16 W ; [96M,128M) bf16 in^T
  const size_t W_F32_BYTES = (size_t)N_OUT_ * N_IN_ * 4;          // 64 MiB
  const size_t W_BF16_OFF  = W_F32_BYTES;                         // 64 MiB
  const size_t BT_OFF      = W_F32_BYTES + W_F32_BYTES / 2;       // 96 MiB
  const size_t NEEDED      = W_F32_BYTES * 2;                     // 128 MiB
  if (ws_size < NEEDED) return;  // fail clean rather than corrupt

  char* ws = (char*)d_ws;
  float*    Wf = (float*)ws;
  ushort_t* Wb = (ushort_t*)(ws + W_BF16_OFF);
  ushort_t* Bt = (ushort_t*)(ws + BT_OFF);

  hipMemsetAsync(Wf, 0, W_F32_BYTES, stream);
  scatter_coo<<<(NNZ_ + 255) / 256, 256, 0, stream>>>(values, rows, cols, Wf);
  convert_w<<<(N_OUT_ * N_IN_ / 4 + 255) / 256, 256, 0, stream>>>(Wf, Wb);
  transpose_bf16<<<dim3(BATCH_ / 32, N_IN_ / 32), dim3(32, 8), 0, stream>>>(inputs, Bt);
  gemm_bias_relu<<<dim3(BATCH_ / 128, N_OUT_ / 128), 256, 0, stream>>>(Wb, Bt, biases, out);
}

// Round 2
// 240.325 us; speedup vs baseline: 1.1444x; 1.1444x over previous
//
#include <hip/hip_runtime.h>
#include <stdint.h>

#define N_OUT_  4096
#define N_IN_   4096
#define BATCH_  4096
#define NNZ_    1600000

typedef unsigned short ushort_t;
typedef float  f32x4  __attribute__((ext_vector_type(4)));
typedef short  short8 __attribute__((ext_vector_type(8)));
typedef __bf16 bf16x8 __attribute__((ext_vector_type(8)));

// RNE f32 -> bf16
__device__ inline ushort_t f32_to_bf16(float f) {
  uint32_t u = __float_as_uint(f);
  uint32_t r = u + 0x7FFFu + ((u >> 16) & 1u);
  return (ushort_t)(r >> 16);
}

// async global->LDS, 16B/lane; LDS dest wave-uniform base + lane*16 (linear)
__device__ inline void gload_lds16(const void* g, void* l) {
  __builtin_amdgcn_global_load_lds(
      (const __attribute__((address_space(1))) void*)g,
      (__attribute__((address_space(3))) void*)l,
      16, 0, 0);
}

__device__ inline f32x4 mfma_bf16(short8 a, short8 b, f32x4 c) {
  return __builtin_amdgcn_mfma_f32_16x16x32_bf16(
      __builtin_bit_cast(bf16x8, a), __builtin_bit_cast(bf16x8, b), c, 0, 0, 0);
}

#define BARRIER() asm volatile("s_barrier" ::: "memory")
template <int N> __device__ __forceinline__ void waitvm() {
  if constexpr (N == 8) asm volatile("s_waitcnt vmcnt(8)" ::: "memory");
  else if constexpr (N == 4) asm volatile("s_waitcnt vmcnt(4)" ::: "memory");
  else asm volatile("s_waitcnt vmcnt(0)" ::: "memory");
}

// ---------------- 1. COO scatter-add into dense f32 W ----------------
__global__ __launch_bounds__(256) void scatter_coo(
    const float* __restrict__ vals, const int* __restrict__ rows,
    const int* __restrict__ cols, float* __restrict__ W) {
  int i = blockIdx.x * 256 + threadIdx.x;
  if (i < NNZ_) atomicAdd(&W[(size_t)rows[i] * N_IN_ + cols[i]], vals[i]);
}

// ---------------- 2. W f32 -> bf16 ----------------
__global__ __launch_bounds__(256) void convert_w(
    const float* __restrict__ Wf, ushort_t* __restrict__ Wb) {
  size_t i = ((size_t)blockIdx.x * 256 + threadIdx.x) * 4;
  float4 f = *(const float4*)(Wf + i);
  ushort4 u;
  u.x = f32_to_bf16(f.x); u.y = f32_to_bf16(f.y);
  u.z = f32_to_bf16(f.z); u.w = f32_to_bf16(f.w);
  *(ushort4*)(Wb + i) = u;
}

// ---------------- 3. inputs [K][N] f32 -> Bt [N][K] bf16 ----------------
__global__ __launch_bounds__(256) void transpose_bf16(
    const float* __restrict__ in, ushort_t* __restrict__ out) {
  __shared__ float tile[32][33];
  const int bx = blockIdx.x * 32, by = blockIdx.y * 32;
  const int tx = threadIdx.x, ty = threadIdx.y;
#pragma unroll
  for (int i = 0; i < 32; i += 8)
    tile[ty + i][tx] = in[(size_t)(by + ty + i) * BATCH_ + bx + tx];
  __syncthreads();
#pragma unroll
  for (int i = 0; i < 32; i += 8)
    out[(size_t)(bx + ty + i) * N_IN_ + by + tx] = f32_to_bf16(tile[tx][ty + i]);
}

// ---------------- 4. 256x256 ring-buffered pipelined GEMM + bias + relu ------
// C[m][n] = relu(sum_k A[m][k]*Bt[n][k] + bias[m])
// BK=32, 4 LDS buffers (ring), counted vmcnt(8) in main loop, T2 XOR swizzle,
// T5 setprio, T1 XCD swizzle. 8 waves: 2(M) x 4(N), each owns 128x64 of C.
#define BM 256
#define BN 256
#define BK 32
#define KTILES 128            // 4096/32
#define TILE_BYTES 32768      // A 16K + B 16K
#define B_OFF 16384

__global__ __launch_bounds__(512, 2) void gemm_bias_relu(
    const ushort_t* __restrict__ A,    // bf16 [N_OUT][N_IN]
    const ushort_t* __restrict__ Bt,   // bf16 [BATCH][N_IN]
    const float* __restrict__ bias,    // [N_OUT]
    float* __restrict__ C) {           // f32 [N_OUT][BATCH]
  __shared__ __align__(16) char smem[4 * TILE_BYTES];  // 128 KiB

  const int tid  = threadIdx.x;
  const int wid  = tid >> 6;
  const int lane = tid & 63;

  // T1: XCD swizzle (nwg=256, 8 XCDs, bijective since 256%8==0)
  const int bid = blockIdx.x;
  const int swz = (bid & 7) * 32 + (bid >> 3);
  const int brow = (swz >> 4) * BM;
  const int bcol = (swz & 15) * BN;

  const int wr = wid >> 2;        // 0..1 -> rows wr*128..+128
  const int wc = wid & 3;         // 0..3 -> cols wc*64..+64
  const int fr = lane & 15;
  const int k0slot = lane >> 4;   // 0..3, k0 = k0slot*8

  // fragment LDS byte offsets within 16KB operand tile; T2 SWZ is an
  // involution: mask source bits 7-8 disjoint from modified bits 4-5.
  int aoff[8], boff[4];
#pragma unroll
  for (int mi = 0; mi < 8; ++mi) {
    int off = (wr * 128 + mi * 16 + fr) * 64 + k0slot * 16;
    aoff[mi] = off ^ (((off >> 7) & 3) << 4);
  }
#pragma unroll
  for (int ni = 0; ni < 4; ++ni) {
    int off = (wc * 64 + ni * 16 + fr) * 64 + k0slot * 16;
    boff[ni] = off ^ (((off >> 7) & 3) << 4);
  }

  // staging: waves 0-3 -> A tile, waves 4-7 -> B tile. 16 chunks of 1KB
  // (16 rows x 64B); wave sw owns chunks 4sw..4sw+3, 2 per phase.
  // Pre-swizzled global source: lane l sources logical elem of swzl.
  const bool isB = wid >= 4;
  const int sw = isB ? wid - 4 : wid;
  const int swzl = lane ^ ((lane >> 3) & 3);
  const int rowInChunk = swzl >> 2;
  const int kelem = (swzl & 3) * 8;
  const ushort_t* gsrc = isB ? Bt : A;
  const size_t laneRowBase =
      (size_t)((isB ? bcol : brow) + sw * 64 + rowInChunk) * N_IN_ + kelem;
  const int ldsOpBase = isB ? B_OFF : 0;

#define STAGE(p, i, t)                                                        \
  gload_lds16(gsrc + laneRowBase + (size_t)(2 * (p) + (i)) * 16 * N_IN_ +     \
                  (size_t)(t) * BK,                                           \
              smem + ((t) & 3) * TILE_BYTES + ldsOpBase +                     \
                  (4 * sw + 2 * (p) + (i)) * 1024)

  f32x4 acc[8][4] = {};

  // prologue: stage tiles 0,1,2 (4 loads/wave each); keep 1,2 in flight
#pragma unroll
  for (int t = 0; t < 3; ++t) {
    STAGE(0, 0, t); STAGE(0, 1, t); STAGE(1, 0, t); STAGE(1, 1, t);
  }
  waitvm<8>();
  BARRIER();

#define TILE_BODY(t, DO_STAGE, WVM)                                           \
  do {                                                                        \
    const char* bufp = &smem[((t) & 3) * TILE_BYTES];                         \
    short8 af[4], bfr[4];                                                     \
    _Pragma("unroll") for (int mi = 0; mi < 4; ++mi)                          \
        af[mi] = *(const short8*)(bufp + aoff[mi]);                           \
    _Pragma("unroll") for (int ni = 0; ni < 4; ++ni)                          \
        bfr[ni] = *(const short8*)(bufp + B_OFF + boff[ni]);                  \
    if (DO_STAGE) { STAGE(0, 0, (t) + 3); STAGE(0, 1, (t) + 3); }             \
    BARRIER();                                                                \
    __builtin_amdgcn_s_setprio(1);                                            \
    _Pragma("unroll") for (int mi = 0; mi < 4; ++mi)                          \
        _Pragma("unroll") for (int ni = 0; ni < 4; ++ni)                      \
            acc[mi][ni] = mfma_bf16(af[mi], bfr[ni], acc[mi][ni]);            \
    __builtin_amdgcn_s_setprio(0);                                            \
    BARRIER();                                                                \
    _Pragma("unroll") for (int mi = 0; mi < 4; ++mi)                          \
        af[mi] = *(const short8*)(bufp + aoff[mi + 4]);                       \
    if (DO_STAGE) { STAGE(1, 0, (t) + 3); STAGE(1, 1, (t) + 3); }             \
    BARRIER();                                                                \
    __builtin_amdgcn_s_setprio(1);                                            \
    _Pragma("unroll") for (int mi = 0; mi < 4; ++mi)                          \
        _Pragma("unroll") for (int ni = 0; ni < 4; ++ni)                      \
            acc[mi + 4][ni] = mfma_bf16(af[mi], bfr[ni], acc[mi + 4][ni]);    \
    __builtin_amdgcn_s_setprio(0);                                            \
    WVM;                                                                      \
    BARRIER();                                                                \
  } while (0)

  for (int t = 0; t < KTILES - 3; ++t) TILE_BODY(t, 1, waitvm<8>());
  TILE_BODY(KTILES - 3, 0, waitvm<4>());
  TILE_BODY(KTILES - 2, 0, waitvm<0>());
  TILE_BODY(KTILES - 1, 0, (void)0);

  // epilogue: C/D map col = lane&15, row = (lane>>4)*4 + reg
  const int r0 = brow + wr * 128 + k0slot * 4;
  const int c0 = bcol + wc * 64 + fr;
#pragma unroll
  for (int mi = 0; mi < 8; ++mi) {
#pragma unroll
    for (int r = 0; r < 4; ++r) {
      const int row = r0 + mi * 16 + r;
      const float b = bias[row];
#pragma unroll
      for (int ni = 0; ni < 4; ++ni) {
        float v = acc[mi][ni][r] + b;
        C[(size_t)row * BATCH_ + c0 + ni * 16] = v > 0.f ? v : 0.f;
      }
    }
  }
#undef TILE_BODY
#undef STAGE
}

extern "C" void kernel_launch(void* const* d_in, const int* in_sizes, int n_in,
                              void* d_out, int out_size, void* d_ws, size_t ws_size,
                              hipStream_t stream) {
  const float* inputs = (const float*)d_in[0];
  const float* values = (const float*)d_in[1];
  const float* biases = (const float*)d_in[2];
  const int*   rows   = (const int*)d_in[3];
  const int*   cols   = (const int*)d_in[4];
  float* out = (float*)d_out;

  const size_t W_F32_BYTES = (size_t)N_OUT_ * N_IN_ * 4;   // 64 MiB
  const size_t W_BF16_OFF  = W_F32_BYTES;                  // 64 MiB
  const size_t BT_OFF      = W_F32_BYTES + W_F32_BYTES / 2;
  const size_t NEEDED      = W_F32_BYTES * 2;              // 128 MiB
  if (ws_size < NEEDED) return;

  char* ws = (char*)d_ws;
  float*    Wf = (float*)ws;
  ushort_t* Wb = (ushort_t*)(ws + W_BF16_OFF);
  ushort_t* Bt = (ushort_t*)(ws + BT_OFF);

  hipMemsetAsync(Wf, 0, W_F32_BYTES, stream);
  scatter_coo<<<(NNZ_ + 255) / 256, 256, 0, stream>>>(values, rows, cols, Wf);
  convert_w<<<(N_OUT_ * N_IN_ / 4 + 255) / 256, 256, 0, stream>>>(Wf, Wb);
  transpose_bf16<<<dim3(BATCH_ / 32, N_IN_ / 32), dim3(32, 8), 0, stream>>>(inputs, Bt);
  gemm_bias_relu<<<dim3(256), 512, 0, stream>>>(Wb, Bt, biases, out);
}

// Round 4
// 236.881 us; speedup vs baseline: 1.1610x; 1.0145x over previous
//
#include <hip/hip_runtime.h>
#include <stdint.h>

#define N_OUT_  4096
#define N_IN_   4096
#define BATCH_  4096
#define NNZ_    1600000

typedef unsigned short ushort_t;
typedef float  f32x4  __attribute__((ext_vector_type(4)));
typedef short  short8 __attribute__((ext_vector_type(8)));
typedef __bf16 bf16x8 __attribute__((ext_vector_type(8)));

// RNE f32 -> bf16
__device__ inline ushort_t f32_to_bf16(float f) {
  uint32_t u = __float_as_uint(f);
  uint32_t r = u + 0x7FFFu + ((u >> 16) & 1u);
  return (ushort_t)(r >> 16);
}

// async global->LDS, 16B/lane; LDS dest wave-uniform base + lane*16 (linear)
__device__ inline void gload_lds16(const void* g, void* l) {
  __builtin_amdgcn_global_load_lds(
      (const __attribute__((address_space(1))) void*)g,
      (__attribute__((address_space(3))) void*)l,
      16, 0, 0);
}

__device__ inline f32x4 mfma_bf16(short8 a, short8 b, f32x4 c) {
  return __builtin_amdgcn_mfma_f32_16x16x32_bf16(
      __builtin_bit_cast(bf16x8, a), __builtin_bit_cast(bf16x8, b), c, 0, 0, 0);
}

#define BARRIER() asm volatile("s_barrier" ::: "memory")
template <int N> __device__ __forceinline__ void waitvm() {
  if constexpr (N == 8)      asm volatile("s_waitcnt vmcnt(8)" ::: "memory");
  else if constexpr (N == 6) asm volatile("s_waitcnt vmcnt(6)" ::: "memory");
  else if constexpr (N == 4) asm volatile("s_waitcnt vmcnt(4)" ::: "memory");
  else                       asm volatile("s_waitcnt vmcnt(0)" ::: "memory");
}

// ---------------- 1. COO scatter-add into dense f32 W (proven path) ---------
__global__ __launch_bounds__(256) void scatter_coo(
    const float* __restrict__ vals, const int* __restrict__ rows,
    const int* __restrict__ cols, float* __restrict__ W) {
  int i = blockIdx.x * 256 + threadIdx.x;
  if (i < NNZ_) atomicAdd(&W[(size_t)rows[i] * N_IN_ + cols[i]], vals[i]);
}

// ---------------- 2. W f32 -> bf16 ----------------
__global__ __launch_bounds__(256) void convert_w(
    const float* __restrict__ Wf, ushort_t* __restrict__ Wb) {
  size_t i = ((size_t)blockIdx.x * 256 + threadIdx.x) * 4;
  float4 f = *(const float4*)(Wf + i);
  ushort4 u;
  u.x = f32_to_bf16(f.x); u.y = f32_to_bf16(f.y);
  u.z = f32_to_bf16(f.z); u.w = f32_to_bf16(f.w);
  *(ushort4*)(Wb + i) = u;
}

// ---------------- 3. inputs [K][N] f32 -> Bt [N][K] bf16 ----------------
__global__ __launch_bounds__(256) void transpose_bf16(
    const float* __restrict__ in, ushort_t* __restrict__ out) {
  __shared__ float tile[32][33];
  const int bx = blockIdx.x * 32, by = blockIdx.y * 32;
  const int tx = threadIdx.x, ty = threadIdx.y;
#pragma unroll
  for (int i = 0; i < 32; i += 8)
    tile[ty + i][tx] = in[(size_t)(by + ty + i) * BATCH_ + bx + tx];
  __syncthreads();
#pragma unroll
  for (int i = 0; i < 32; i += 8)
    out[(size_t)(bx + ty + i) * N_IN_ + by + tx] = f32_to_bf16(tile[tx][ty + i]);
}

// ---------------- 4. 256x256 ring-4 GEMM, read-ahead pipelined phases -------
// C[m][n] = relu(sum_k A[m][k]*Bt[n][k] + bias[m])
// Per tile (BK=32), 2 phases; phase ds_reads feed the NEXT MFMA cluster
// (separate register sets), so the compiler's counted lgkmcnt leaves them in
// flight while the current MFMA cluster runs. Counted vmcnt(6) in main loop.
#define BM 256
#define BN 256
#define BK 32
#define KTILES 128            // 4096/32
#define TILE_BYTES 32768      // A 16K + B 16K
#define B_OFF 16384

__global__ __launch_bounds__(512, 2) void gemm_bias_relu(
    const ushort_t* __restrict__ A,    // bf16 [N_OUT][N_IN]
    const ushort_t* __restrict__ Bt,   // bf16 [BATCH][N_IN]
    const float* __restrict__ bias,    // [N_OUT]
    float* __restrict__ C) {           // f32 [N_OUT][BATCH]
  __shared__ __align__(16) char smem[4 * TILE_BYTES];  // 128 KiB

  const int tid  = threadIdx.x;
  const int wid  = tid >> 6;
  const int lane = tid & 63;

  // T1: XCD swizzle (nwg=256, 8 XCDs, bijective)
  const int bid = blockIdx.x;
  const int swz = (bid & 7) * 32 + (bid >> 3);
  const int brow = (swz >> 4) * BM;
  const int bcol = (swz & 15) * BN;

  const int wr = wid >> 2;        // 0..1 -> rows wr*128..+128
  const int wc = wid & 3;         // 0..3 -> cols wc*64..+64
  const int fr = lane & 15;
  const int k0slot = lane >> 4;   // 0..3

  // frag LDS byte offsets (T2 XOR swizzle: bits7-8 -> bits4-5, involution)
  int aoff[8], boff[4];
#pragma unroll
  for (int mi = 0; mi < 8; ++mi) {
    int off = (wr * 128 + mi * 16 + fr) * 64 + k0slot * 16;
    aoff[mi] = off ^ (((off >> 7) & 3) << 4);
  }
#pragma unroll
  for (int ni = 0; ni < 4; ++ni) {
    int off = (wc * 64 + ni * 16 + fr) * 64 + k0slot * 16;
    boff[ni] = off ^ (((off >> 7) & 3) << 4);
  }

  // staging: waves 0-3 -> A, 4-7 -> B; wave sw owns 1KB chunks 4sw..4sw+3,
  // 2 per phase; pre-swizzled per-lane global source (rule #21)
  const bool isB = wid >= 4;
  const int sw = isB ? wid - 4 : wid;
  const int swzl = lane ^ ((lane >> 3) & 3);
  const int rowInChunk = swzl >> 2;
  const int kelem = (swzl & 3) * 8;
  const ushort_t* gsrc = isB ? Bt : A;
  const size_t laneRowBase =
      (size_t)((isB ? bcol : brow) + sw * 64 + rowInChunk) * N_IN_ + kelem;
  const int ldsOpBase = isB ? B_OFF : 0;

#define STAGE(p, i, t)                                                        \
  gload_lds16(gsrc + laneRowBase + (size_t)(2 * (p) + (i)) * 16 * N_IN_ +     \
                  (size_t)(t) * BK,                                           \
              smem + ((t) & 3) * TILE_BYTES + ldsOpBase +                     \
                  (4 * sw + 2 * (p) + (i)) * 1024)

  f32x4 acc[8][4] = {};
  short8 aE[4], bE[4], aO[4], bO[4], aH[4];  // aH: intra-tile only (ph1->ph2)

  // prologue: stage tiles 0,1,2; wait tile 0; preload tile-0 ph1 frags
#pragma unroll
  for (int t = 0; t < 3; ++t) {
    STAGE(0, 0, t); STAGE(0, 1, t); STAGE(1, 0, t); STAGE(1, 1, t);
  }
  waitvm<8>();
  BARRIER();
#pragma unroll
  for (int j = 0; j < 4; ++j) {
    aE[j] = *(const short8*)(smem + aoff[j]);
    bE[j] = *(const short8*)(smem + B_OFF + boff[j]);
  }

// TILE: ph1 {read A-hi(buf t) | stage h0(t+3) | vmcnt | barrier | MFMA AL x BB}
//       ph2 {read next-tile AL'/BB'(buf t+1) | stage h1(t+3) | barrier |
//            MFMA aH x BB} | end barrier (protects buf t from t+1's staging)
#define TILE(t, AL, BB, ALn, BBn, S_ON, VM, RA_ON)                            \
  do {                                                                        \
    const char* buf  = &smem[((t) & 3) * TILE_BYTES];                         \
    const char* bufn = &smem[(((t) + 1) & 3) * TILE_BYTES];                   \
    _Pragma("unroll") for (int j = 0; j < 4; ++j)                             \
        aH[j] = *(const short8*)(buf + aoff[j + 4]);                          \
    if (S_ON) { STAGE(0, 0, (t) + 3); STAGE(0, 1, (t) + 3); }                 \
    VM;                                                                       \
    BARRIER();                                                                \
    __builtin_amdgcn_s_setprio(1);                                            \
    _Pragma("unroll") for (int mi = 0; mi < 4; ++mi)                          \
        _Pragma("unroll") for (int ni = 0; ni < 4; ++ni)                      \
            acc[mi][ni] = mfma_bf16(AL[mi], BB[ni], acc[mi][ni]);             \
    __builtin_amdgcn_s_setprio(0);                                            \
    if (RA_ON) {                                                              \
      _Pragma("unroll") for (int j = 0; j < 4; ++j)                           \
          ALn[j] = *(const short8*)(bufn + aoff[j]);                          \
      _Pragma("unroll") for (int j = 0; j < 4; ++j)                           \
          BBn[j] = *(const short8*)(bufn + B_OFF + boff[j]);                  \
    }                                                                         \
    if (S_ON) { STAGE(1, 0, (t) + 3); STAGE(1, 1, (t) + 3); }                 \
    BARRIER();                                                                \
    __builtin_amdgcn_s_setprio(1);                                            \
    _Pragma("unroll") for (int mi = 0; mi < 4; ++mi)                          \
        _Pragma("unroll") for (int ni = 0; ni < 4; ++ni)                      \
            acc[mi + 4][ni] = mfma_bf16(aH[mi], BB[ni], acc[mi + 4][ni]);     \
    __builtin_amdgcn_s_setprio(0);                                            \
    BARRIER();                                                                \
  } while (0)

  // main: tiles 0..123 in E/O pairs; peel 124-127 (stage stops, vmcnt 6/4/0)
  for (int t = 0; t < KTILES - 4; t += 2) {
    TILE(t,     aE, bE, aO, bO, 1, waitvm<6>(), 1);
    TILE(t + 1, aO, bO, aE, bE, 1, waitvm<6>(), 1);
  }
  TILE(KTILES - 4, aE, bE, aO, bO, 1, waitvm<6>(), 1);
  TILE(KTILES - 3, aO, bO, aE, bE, 0, waitvm<4>(), 1);
  TILE(KTILES - 2, aE, bE, aO, bO, 0, waitvm<0>(), 1);
  TILE(KTILES - 1, aO, bO, aE, bE, 0, (void)0,     0);

  // epilogue: C/D map col = lane&15, row = (lane>>4)*4 + reg
  const int r0 = brow + wr * 128 + k0slot * 4;
  const int c0 = bcol + wc * 64 + fr;
#pragma unroll
  for (int mi = 0; mi < 8; ++mi) {
#pragma unroll
    for (int r = 0; r < 4; ++r) {
      const int row = r0 + mi * 16 + r;
      const float b = bias[row];
#pragma unroll
      for (int ni = 0; ni < 4; ++ni) {
        float v = acc[mi][ni][r] + b;
        C[(size_t)row * BATCH_ + c0 + ni * 16] = v > 0.f ? v : 0.f;
      }
    }
  }
#undef TILE
#undef STAGE
}

extern "C" void kernel_launch(void* const* d_in, const int* in_sizes, int n_in,
                              void* d_out, int out_size, void* d_ws, size_t ws_size,
                              hipStream_t stream) {
  const float* inputs = (const float*)d_in[0];
  const float* values = (const float*)d_in[1];
  const float* biases = (const float*)d_in[2];
  const int*   rows   = (const int*)d_in[3];
  const int*   cols   = (const int*)d_in[4];
  float* out = (float*)d_out;

  // layout: [0,64M) f32 W ; [64M,96M) bf16 W ; [96M,128M) bf16 in^T
  const size_t W_F32_BYTES = (size_t)N_OUT_ * N_IN_ * 4;
  if (ws_size < 2 * W_F32_BYTES) return;
  char* ws = (char*)d_ws;
  float*    Wf = (float*)ws;
  ushort_t* Wb = (ushort_t*)(ws + W_F32_BYTES);
  ushort_t* Bt = (ushort_t*)(ws + W_F32_BYTES + W_F32_BYTES / 2);

  hipMemsetAsync(Wf, 0, W_F32_BYTES, stream);
  scatter_coo<<<(NNZ_ + 255) / 256, 256, 0, stream>>>(values, rows, cols, Wf);
  convert_w<<<(N_OUT_ * N_IN_ / 4 + 255) / 256, 256, 0, stream>>>(Wf, Wb);
  transpose_bf16<<<dim3(BATCH_ / 32, N_IN_ / 32), dim3(32, 8), 0, stream>>>(inputs, Bt);
  gemm_bias_relu<<<dim3(256), 512, 0, stream>>>(Wb, Bt, biases, out);
}

// Round 5
// 230.609 us; speedup vs baseline: 1.1926x; 1.0272x over previous
//
#include <hip/hip_runtime.h>
#include <stdint.h>

#define N_OUT_  4096
#define N_IN_   4096
#define BATCH_  4096
#define NNZ_    1600000

typedef unsigned short ushort_t;
typedef float  f32x4  __attribute__((ext_vector_type(4)));
typedef short  short8 __attribute__((ext_vector_type(8)));
typedef __bf16 bf16x8 __attribute__((ext_vector_type(8)));

// RNE f32 -> bf16
__device__ inline ushort_t f32_to_bf16(float f) {
  uint32_t u = __float_as_uint(f);
  uint32_t r = u + 0x7FFFu + ((u >> 16) & 1u);
  return (ushort_t)(r >> 16);
}

// async global->LDS, 16B/lane; LDS dest wave-uniform base + lane*16 (linear)
__device__ inline void gload_lds16(const void* g, void* l) {
  __builtin_amdgcn_global_load_lds(
      (const __attribute__((address_space(1))) void*)g,
      (__attribute__((address_space(3))) void*)l,
      16, 0, 0);
}

__device__ inline f32x4 mfma_bf16(short8 a, short8 b, f32x4 c) {
  return __builtin_amdgcn_mfma_f32_16x16x32_bf16(
      __builtin_bit_cast(bf16x8, a), __builtin_bit_cast(bf16x8, b), c, 0, 0, 0);
}

#define BARRIER() asm volatile("s_barrier" ::: "memory")
template <int N> __device__ __forceinline__ void waitvm() {
  if constexpr (N == 8)      asm volatile("s_waitcnt vmcnt(8)" ::: "memory");
  else if constexpr (N == 6) asm volatile("s_waitcnt vmcnt(6)" ::: "memory");
  else if constexpr (N == 4) asm volatile("s_waitcnt vmcnt(4)" ::: "memory");
  else                       asm volatile("s_waitcnt vmcnt(0)" ::: "memory");
}

// ---------------- 1. COO scatter-add into dense f32 W (proven path) ---------
__global__ __launch_bounds__(256) void scatter_coo(
    const float* __restrict__ vals, const int* __restrict__ rows,
    const int* __restrict__ cols, float* __restrict__ W) {
  int i = blockIdx.x * 256 + threadIdx.x;
  if (i < NNZ_) atomicAdd(&W[(size_t)rows[i] * N_IN_ + cols[i]], vals[i]);
}

// ---------------- 2. W f32 -> bf16 ----------------
__global__ __launch_bounds__(256) void convert_w(
    const float* __restrict__ Wf, ushort_t* __restrict__ Wb) {
  size_t i = ((size_t)blockIdx.x * 256 + threadIdx.x) * 4;
  float4 f = *(const float4*)(Wf + i);
  ushort4 u;
  u.x = f32_to_bf16(f.x); u.y = f32_to_bf16(f.y);
  u.z = f32_to_bf16(f.z); u.w = f32_to_bf16(f.w);
  *(ushort4*)(Wb + i) = u;
}

// ---------------- 3. inputs [K][N] f32 -> Bt [N][K] bf16 ----------------
__global__ __launch_bounds__(256) void transpose_bf16(
    const float* __restrict__ in, ushort_t* __restrict__ out) {
  __shared__ float tile[32][33];
  const int bx = blockIdx.x * 32, by = blockIdx.y * 32;
  const int tx = threadIdx.x, ty = threadIdx.y;
#pragma unroll
  for (int i = 0; i < 32; i += 8)
    tile[ty + i][tx] = in[(size_t)(by + ty + i) * BATCH_ + bx + tx];
  __syncthreads();
#pragma unroll
  for (int i = 0; i < 32; i += 8)
    out[(size_t)(bx + ty + i) * N_IN_ + by + tx] = f32_to_bf16(tile[tx][ty + i]);
}

// ---------------- 4. 256x256 ring-4 GEMM, 2 barriers/tile -------------------
// C[m][n] = relu(sum_k A[m][k]*Bt[n][k] + bias[m])
// Per tile: {aH reads | stage h0 | vmcnt(6) | barrier |
//            32 MFMA ∥ RA reads ∥ stage h1 (ONE scheduling region) | barrier}
// Counted vmcnt (never 0 in main loop); T1 XCD swizzle; T2 LDS XOR swizzle;
// T5 setprio around MFMA clusters.
#define BM 256
#define BN 256
#define BK 32
#define KTILES 128            // 4096/32
#define TILE_BYTES 32768      // A 16K + B 16K
#define B_OFF 16384

__global__ __launch_bounds__(512, 2) void gemm_bias_relu(
    const ushort_t* __restrict__ A,    // bf16 [N_OUT][N_IN]
    const ushort_t* __restrict__ Bt,   // bf16 [BATCH][N_IN]
    const float* __restrict__ bias,    // [N_OUT]
    float* __restrict__ C) {           // f32 [N_OUT][BATCH]
  __shared__ __align__(16) char smem[4 * TILE_BYTES];  // 128 KiB

  const int tid  = threadIdx.x;
  const int wid  = tid >> 6;
  const int lane = tid & 63;

  // T1: XCD swizzle (nwg=256, 8 XCDs, bijective)
  const int bid = blockIdx.x;
  const int swz = (bid & 7) * 32 + (bid >> 3);
  const int brow = (swz >> 4) * BM;
  const int bcol = (swz & 15) * BN;

  const int wr = wid >> 2;        // 0..1 -> rows wr*128..+128
  const int wc = wid & 3;         // 0..3 -> cols wc*64..+64
  const int fr = lane & 15;
  const int k0slot = lane >> 4;   // 0..3

  // frag LDS byte offsets (T2 XOR swizzle: bits7-8 -> bits4-5, involution)
  int aoff[8], boff[4];
#pragma unroll
  for (int mi = 0; mi < 8; ++mi) {
    int off = (wr * 128 + mi * 16 + fr) * 64 + k0slot * 16;
    aoff[mi] = off ^ (((off >> 7) & 3) << 4);
  }
#pragma unroll
  for (int ni = 0; ni < 4; ++ni) {
    int off = (wc * 64 + ni * 16 + fr) * 64 + k0slot * 16;
    boff[ni] = off ^ (((off >> 7) & 3) << 4);
  }

  // staging: waves 0-3 -> A, 4-7 -> B; wave sw owns 1KB chunks 4sw..4sw+3,
  // 2 per half; pre-swizzled per-lane global source (rule #21)
  const bool isB = wid >= 4;
  const int sw = isB ? wid - 4 : wid;
  const int swzl = lane ^ ((lane >> 3) & 3);
  const int rowInChunk = swzl >> 2;
  const int kelem = (swzl & 3) * 8;
  const ushort_t* gsrc = isB ? Bt : A;
  const size_t laneRowBase =
      (size_t)((isB ? bcol : brow) + sw * 64 + rowInChunk) * N_IN_ + kelem;
  const int ldsOpBase = isB ? B_OFF : 0;

#define STAGE(p, i, t)                                                        \
  gload_lds16(gsrc + laneRowBase + (size_t)(2 * (p) + (i)) * 16 * N_IN_ +     \
                  (size_t)(t) * BK,                                           \
              smem + ((t) & 3) * TILE_BYTES + ldsOpBase +                     \
                  (4 * sw + 2 * (p) + (i)) * 1024)

  f32x4 acc[8][4] = {};
  short8 aE[4], bE[4], aO[4], bO[4], aH[4];  // aH: intra-tile only

  // prologue: stage tiles 0,1,2; wait tile 0; preload tile-0 lo frags
#pragma unroll
  for (int t = 0; t < 3; ++t) {
    STAGE(0, 0, t); STAGE(0, 1, t); STAGE(1, 0, t); STAGE(1, 1, t);
  }
  waitvm<8>();
  BARRIER();
#pragma unroll
  for (int j = 0; j < 4; ++j) {
    aE[j] = *(const short8*)(smem + aoff[j]);
    bE[j] = *(const short8*)(smem + B_OFF + boff[j]);
  }

// TILE: pre-barrier {aH reads (buf t) | stage h0(t+3) | vmcnt | barrier};
// then ONE region: cluster1(AL×BB) | RA reads(buf t+1) | stage h1(t+3) |
// cluster2(aH×BB); end barrier (ring reuse guard).
#define TILE(t, AL, BB, ALn, BBn, S_ON, VM, RA_ON)                            \
  do {                                                                        \
    const char* buf  = &smem[((t) & 3) * TILE_BYTES];                         \
    const char* bufn = &smem[(((t) + 1) & 3) * TILE_BYTES];                   \
    _Pragma("unroll") for (int j = 0; j < 4; ++j)                             \
        aH[j] = *(const short8*)(buf + aoff[j + 4]);                          \
    if (S_ON) { STAGE(0, 0, (t) + 3); STAGE(0, 1, (t) + 3); }                 \
    VM;                                                                       \
    BARRIER();                                                                \
    __builtin_amdgcn_s_setprio(1);                                            \
    _Pragma("unroll") for (int mi = 0; mi < 4; ++mi)                          \
        _Pragma("unroll") for (int ni = 0; ni < 4; ++ni)                      \
            acc[mi][ni] = mfma_bf16(AL[mi], BB[ni], acc[mi][ni]);             \
    __builtin_amdgcn_s_setprio(0);                                            \
    if (RA_ON) {                                                              \
      _Pragma("unroll") for (int j = 0; j < 4; ++j)                           \
          ALn[j] = *(const short8*)(bufn + aoff[j]);                          \
      _Pragma("unroll") for (int j = 0; j < 4; ++j)                           \
          BBn[j] = *(const short8*)(bufn + B_OFF + boff[j]);                  \
    }                                                                         \
    if (S_ON) { STAGE(1, 0, (t) + 3); STAGE(1, 1, (t) + 3); }                 \
    __builtin_amdgcn_s_setprio(1);                                            \
    _Pragma("unroll") for (int mi = 0; mi < 4; ++mi)                          \
        _Pragma("unroll") for (int ni = 0; ni < 4; ++ni)                      \
            acc[mi + 4][ni] = mfma_bf16(aH[mi], BB[ni], acc[mi + 4][ni]);     \
    __builtin_amdgcn_s_setprio(0);                                            \
    BARRIER();                                                                \
  } while (0)

  // main: tiles 0..123 in E/O pairs; peel 124-127 (stage stops, vmcnt 6/4/0)
  for (int t = 0; t < KTILES - 4; t += 2) {
    TILE(t,     aE, bE, aO, bO, 1, waitvm<6>(), 1);
    TILE(t + 1, aO, bO, aE, bE, 1, waitvm<6>(), 1);
  }
  TILE(KTILES - 4, aE, bE, aO, bO, 1, waitvm<6>(), 1);
  TILE(KTILES - 3, aO, bO, aE, bE, 0, waitvm<4>(), 1);
  TILE(KTILES - 2, aE, bE, aO, bO, 0, waitvm<0>(), 1);
  TILE(KTILES - 1, aO, bO, aE, bE, 0, (void)0,     0);

  // epilogue: C/D map col = lane&15, row = (lane>>4)*4 + reg
  const int r0 = brow + wr * 128 + k0slot * 4;
  const int c0 = bcol + wc * 64 + fr;
#pragma unroll
  for (int mi = 0; mi < 8; ++mi) {
#pragma unroll
    for (int r = 0; r < 4; ++r) {
      const int row = r0 + mi * 16 + r;
      const float b = bias[row];
#pragma unroll
      for (int ni = 0; ni < 4; ++ni) {
        float v = acc[mi][ni][r] + b;
        C[(size_t)row * BATCH_ + c0 + ni * 16] = v > 0.f ? v : 0.f;
      }
    }
  }
#undef TILE
#undef STAGE
}

extern "C" void kernel_launch(void* const* d_in, const int* in_sizes, int n_in,
                              void* d_out, int out_size, void* d_ws, size_t ws_size,
                              hipStream_t stream) {
  const float* inputs = (const float*)d_in[0];
  const float* values = (const float*)d_in[1];
  const float* biases = (const float*)d_in[2];
  const int*   rows   = (const int*)d_in[3];
  const int*   cols   = (const int*)d_in[4];
  float* out = (float*)d_out;

  // layout: [0,64M) f32 W ; [64M,96M) bf16 W ; [96M,128M) bf16 in^T
  const size_t W_F32_BYTES = (size_t)N_OUT_ * N_IN_ * 4;
  if (ws_size < 2 * W_F32_BYTES) return;
  char* ws = (char*)d_ws;
  float*    Wf = (float*)ws;
  ushort_t* Wb = (ushort_t*)(ws + W_F32_BYTES);
  ushort_t* Bt = (ushort_t*)(ws + W_F32_BYTES + W_F32_BYTES / 2);

  hipMemsetAsync(Wf, 0, W_F32_BYTES, stream);
  scatter_coo<<<(NNZ_ + 255) / 256, 256, 0, stream>>>(values, rows, cols, Wf);
  convert_w<<<(N_OUT_ * N_IN_ / 4 + 255) / 256, 256, 0, stream>>>(Wf, Wb);
  transpose_bf16<<<dim3(BATCH_ / 32, N_IN_ / 32), dim3(32, 8), 0, stream>>>(inputs, Bt);
  gemm_bias_relu<<<dim3(256), 512, 0, stream>>>(Wb, Bt, biases, out);
}

// Round 6
// 217.730 us; speedup vs baseline: 1.2631x; 1.0592x over previous
//
#include <hip/hip_runtime.h>
#include <stdint.h>

#define N_OUT_  4096
#define N_IN_   4096
#define BATCH_  4096
#define NNZ_    1600000

typedef unsigned short ushort_t;
typedef float  f32x4  __attribute__((ext_vector_type(4)));
typedef short  short8 __attribute__((ext_vector_type(8)));
typedef __bf16 bf16x8 __attribute__((ext_vector_type(8)));

// RNE f32 -> bf16
__device__ inline ushort_t f32_to_bf16(float f) {
  uint32_t u = __float_as_uint(f);
  uint32_t r = u + 0x7FFFu + ((u >> 16) & 1u);
  return (ushort_t)(r >> 16);
}
__device__ inline float bf16_to_f32(ushort_t h) {
  return __uint_as_float(((uint32_t)h) << 16);
}

// async global->LDS, 16B/lane; LDS dest wave-uniform base + lane*16 (linear)
__device__ inline void gload_lds16(const void* g, void* l) {
  __builtin_amdgcn_global_load_lds(
      (const __attribute__((address_space(1))) void*)g,
      (__attribute__((address_space(3))) void*)l,
      16, 0, 0);
}

__device__ inline f32x4 mfma_bf16(short8 a, short8 b, f32x4 c) {
  return __builtin_amdgcn_mfma_f32_16x16x32_bf16(
      __builtin_bit_cast(bf16x8, a), __builtin_bit_cast(bf16x8, b), c, 0, 0, 0);
}

#define BARRIER() asm volatile("s_barrier" ::: "memory")
template <int N> __device__ __forceinline__ void waitvm() {
  if constexpr (N == 8)      asm volatile("s_waitcnt vmcnt(8)" ::: "memory");
  else if constexpr (N == 6) asm volatile("s_waitcnt vmcnt(6)" ::: "memory");
  else if constexpr (N == 4) asm volatile("s_waitcnt vmcnt(4)" ::: "memory");
  else                       asm volatile("s_waitcnt vmcnt(0)" ::: "memory");
}

// ------- 1. COO scatter-add directly into bf16 W via u32 CAS loop ----------
// Duplicates sum in bf16 (per-add rounding); ~5% of nnz slots, ~1ulp error.
__global__ __launch_bounds__(256) void scatter_coo_cas(
    const float* __restrict__ vals, const int* __restrict__ rows,
    const int* __restrict__ cols, uint32_t* __restrict__ W32) {
  int i = blockIdx.x * 256 + threadIdx.x;
  if (i >= NNZ_) return;
  const size_t idx = (size_t)rows[i] * N_IN_ + cols[i];
  const float v = vals[i];
  uint32_t* p = &W32[idx >> 1];
  const bool hi = (idx & 1) != 0;
  uint32_t old = *p, assumed;
  do {
    assumed = old;
    ushort_t h = hi ? (ushort_t)(assumed >> 16) : (ushort_t)(assumed & 0xFFFFu);
    ushort_t nh = f32_to_bf16(bf16_to_f32(h) + v);
    uint32_t nw = hi ? ((assumed & 0x0000FFFFu) | ((uint32_t)nh << 16))
                     : ((assumed & 0xFFFF0000u) | (uint32_t)nh);
    old = atomicCAS(p, assumed, nw);
  } while (old != assumed);
}

// ---------------- 2. inputs [K][N] f32 -> Bt [N][K] bf16 ----------------
__global__ __launch_bounds__(256) void transpose_bf16(
    const float* __restrict__ in, ushort_t* __restrict__ out) {
  __shared__ float tile[32][33];
  const int bx = blockIdx.x * 32, by = blockIdx.y * 32;
  const int tx = threadIdx.x, ty = threadIdx.y;
#pragma unroll
  for (int i = 0; i < 32; i += 8)
    tile[ty + i][tx] = in[(size_t)(by + ty + i) * BATCH_ + bx + tx];
  __syncthreads();
#pragma unroll
  for (int i = 0; i < 32; i += 8)
    out[(size_t)(bx + ty + i) * N_IN_ + by + tx] = f32_to_bf16(tile[tx][ty + i]);
}

// ---------------- 3. 256x256 ring-4 GEMM, m201-grain phases -----------------
// C[m][n] = relu(sum_k A[m][k]*Bt[n][k] + bias[m])
// Per tile (BK=32), 2 phases at m201 grain:
//  P1 {aH reads | stage h0 | vmcnt(6) | barrier | ALn reads + 16 MFMA | barrier}
//  P2 {BBn reads | stage h1 | barrier | 16 MFMA | barrier(ring guard)}
// Next-buf reads always after a barrier preceded by every wave's vmcnt.
#define BM 256
#define BN 256
#define BK 32
#define KTILES 128            // 4096/32
#define TILE_BYTES 32768      // A 16K + B 16K
#define B_OFF 16384

__global__ __launch_bounds__(512, 2) void gemm_bias_relu(
    const ushort_t* __restrict__ A,    // bf16 [N_OUT][N_IN]
    const ushort_t* __restrict__ Bt,   // bf16 [BATCH][N_IN]
    const float* __restrict__ bias,    // [N_OUT]
    float* __restrict__ C) {           // f32 [N_OUT][BATCH]
  __shared__ __align__(16) char smem[4 * TILE_BYTES];  // 128 KiB

  const int tid  = threadIdx.x;
  const int wid  = tid >> 6;
  const int lane = tid & 63;

  // T1: XCD swizzle (nwg=256, 8 XCDs, bijective)
  const int bid = blockIdx.x;
  const int swz = (bid & 7) * 32 + (bid >> 3);
  const int brow = (swz >> 4) * BM;
  const int bcol = (swz & 15) * BN;

  const int wr = wid >> 2;        // 0..1 -> rows wr*128..+128
  const int wc = wid & 3;         // 0..3 -> cols wc*64..+64
  const int fr = lane & 15;
  const int k0slot = lane >> 4;   // 0..3

  // frag LDS byte offsets (T2 XOR swizzle: bits7-8 -> bits4-5, involution)
  int aoff[8], boff[4];
#pragma unroll
  for (int mi = 0; mi < 8; ++mi) {
    int off = (wr * 128 + mi * 16 + fr) * 64 + k0slot * 16;
    aoff[mi] = off ^ (((off >> 7) & 3) << 4);
  }
#pragma unroll
  for (int ni = 0; ni < 4; ++ni) {
    int off = (wc * 64 + ni * 16 + fr) * 64 + k0slot * 16;
    boff[ni] = off ^ (((off >> 7) & 3) << 4);
  }

  // staging: waves 0-3 -> A, 4-7 -> B; wave sw owns 1KB chunks 4sw..4sw+3,
  // 2 per half; pre-swizzled per-lane global source (rule #21)
  const bool isB = wid >= 4;
  const int sw = isB ? wid - 4 : wid;
  const int swzl = lane ^ ((lane >> 3) & 3);
  const int rowInChunk = swzl >> 2;
  const int kelem = (swzl & 3) * 8;
  const ushort_t* gsrc = isB ? Bt : A;
  const size_t laneRowBase =
      (size_t)((isB ? bcol : brow) + sw * 64 + rowInChunk) * N_IN_ + kelem;
  const int ldsOpBase = isB ? B_OFF : 0;

#define STAGE(p, i, t)                                                        \
  gload_lds16(gsrc + laneRowBase + (size_t)(2 * (p) + (i)) * 16 * N_IN_ +     \
                  (size_t)(t) * BK,                                           \
              smem + ((t) & 3) * TILE_BYTES + ldsOpBase +                     \
                  (4 * sw + 2 * (p) + (i)) * 1024)

  f32x4 acc[8][4] = {};
  short8 aE[4], bE[4], aO[4], bO[4], aH[4];  // aH: intra-tile only

  // prologue: stage tiles 0,1,2; wait tile 0 (12 outstanding -> vmcnt(8));
  // barrier; preload tile-0 lo frags
#pragma unroll
  for (int t = 0; t < 3; ++t) {
    STAGE(0, 0, t); STAGE(0, 1, t); STAGE(1, 0, t); STAGE(1, 1, t);
  }
  waitvm<8>();
  BARRIER();
#pragma unroll
  for (int j = 0; j < 4; ++j) {
    aE[j] = *(const short8*)(smem + aoff[j]);
    bE[j] = *(const short8*)(smem + B_OFF + boff[j]);
  }

#define TILE(t, AL, BB, ALn, BBn, S_ON, VM, RA_ON)                            \
  do {                                                                        \
    const char* buf  = &smem[((t) & 3) * TILE_BYTES];                         \
    const char* bufn = &smem[(((t) + 1) & 3) * TILE_BYTES];                   \
    /* P1 */                                                                  \
    _Pragma("unroll") for (int j = 0; j < 4; ++j)                             \
        aH[j] = *(const short8*)(buf + aoff[j + 4]);                          \
    if (S_ON) { STAGE(0, 0, (t) + 3); STAGE(0, 1, (t) + 3); }                 \
    VM;                                                                       \
    BARRIER();                                                                \
    if (RA_ON) {                                                              \
      _Pragma("unroll") for (int j = 0; j < 4; ++j)                           \
          ALn[j] = *(const short8*)(bufn + aoff[j]);                          \
    }                                                                         \
    __builtin_amdgcn_s_setprio(1);                                            \
    _Pragma("unroll") for (int mi = 0; mi < 4; ++mi)                          \
        _Pragma("unroll") for (int ni = 0; ni < 4; ++ni)                      \
            acc[mi][ni] = mfma_bf16(AL[mi], BB[ni], acc[mi][ni]);             \
    __builtin_amdgcn_s_setprio(0);                                            \
    BARRIER();                                                                \
    /* P2 */                                                                  \
    if (RA_ON) {                                                              \
      _Pragma("unroll") for (int j = 0; j < 4; ++j)                           \
          BBn[j] = *(const short8*)(bufn + B_OFF + boff[j]);                  \
    }                                                                         \
    if (S_ON) { STAGE(1, 0, (t) + 3); STAGE(1, 1, (t) + 3); }                 \
    BARRIER();                                                                \
    __builtin_amdgcn_s_setprio(1);                                            \
    _Pragma("unroll") for (int mi = 0; mi < 4; ++mi)                          \
        _Pragma("unroll") for (int ni = 0; ni < 4; ++ni)                      \
            acc[mi + 4][ni] = mfma_bf16(aH[mi], BB[ni], acc[mi + 4][ni]);     \
    __builtin_amdgcn_s_setprio(0);                                            \
    BARRIER();                                                                \
  } while (0)

  // main: tiles 0..123 in E/O pairs; peel 124-127 (stage stops, vmcnt 6/4/0)
  for (int t = 0; t < KTILES - 4; t += 2) {
    TILE(t,     aE, bE, aO, bO, 1, waitvm<6>(), 1);
    TILE(t + 1, aO, bO, aE, bE, 1, waitvm<6>(), 1);
  }
  TILE(KTILES - 4, aE, bE, aO, bO, 1, waitvm<6>(), 1);
  TILE(KTILES - 3, aO, bO, aE, bE, 0, waitvm<4>(), 1);
  TILE(KTILES - 2, aE, bE, aO, bO, 0, waitvm<0>(), 1);
  TILE(KTILES - 1, aO, bO, aE, bE, 0, (void)0,     0);

  // epilogue: C/D map col = lane&15, row = (lane>>4)*4 + reg
  const int r0 = brow + wr * 128 + k0slot * 4;
  const int c0 = bcol + wc * 64 + fr;
#pragma unroll
  for (int mi = 0; mi < 8; ++mi) {
#pragma unroll
    for (int r = 0; r < 4; ++r) {
      const int row = r0 + mi * 16 + r;
      const float b = bias[row];
#pragma unroll
      for (int ni = 0; ni < 4; ++ni) {
        float v = acc[mi][ni][r] + b;
        C[(size_t)row * BATCH_ + c0 + ni * 16] = v > 0.f ? v : 0.f;
      }
    }
  }
#undef TILE
#undef STAGE
}

extern "C" void kernel_launch(void* const* d_in, const int* in_sizes, int n_in,
                              void* d_out, int out_size, void* d_ws, size_t ws_size,
                              hipStream_t stream) {
  const float* inputs = (const float*)d_in[0];
  const float* values = (const float*)d_in[1];
  const float* biases = (const float*)d_in[2];
  const int*   rows   = (const int*)d_in[3];
  const int*   cols   = (const int*)d_in[4];
  float* out = (float*)d_out;

  // layout: [0,32M) bf16 W ; [32M,64M) bf16 in^T
  const size_t W_BF16_BYTES = (size_t)N_OUT_ * N_IN_ * 2;  // 32 MiB
  if (ws_size < 2 * W_BF16_BYTES) return;
  char* ws = (char*)d_ws;
  ushort_t* Wb = (ushort_t*)ws;
  ushort_t* Bt = (ushort_t*)(ws + W_BF16_BYTES);

  hipMemsetAsync(Wb, 0, W_BF16_BYTES, stream);
  scatter_coo_cas<<<(NNZ_ + 255) / 256, 256, 0, stream>>>(values, rows, cols,
                                                          (uint32_t*)Wb);
  transpose_bf16<<<dim3(BATCH_ / 32, N_IN_ / 32), dim3(32, 8), 0, stream>>>(inputs, Bt);
  gemm_bias_relu<<<dim3(256), 512, 0, stream>>>(Wb, Bt, biases, out);
}

// Round 7
// 210.630 us; speedup vs baseline: 1.3057x; 1.0337x over previous
//
#include <hip/hip_runtime.h>
#include <stdint.h>

#define N_OUT_  4096
#define N_IN_   4096
#define BATCH_  4096
#define NNZ_    1600000

typedef unsigned short ushort_t;
typedef float  f32x4  __attribute__((ext_vector_type(4)));
typedef short  short8 __attribute__((ext_vector_type(8)));
typedef __bf16 bf16x8 __attribute__((ext_vector_type(8)));

// RNE f32 -> bf16
__device__ inline ushort_t f32_to_bf16(float f) {
  uint32_t u = __float_as_uint(f);
  uint32_t r = u + 0x7FFFu + ((u >> 16) & 1u);
  return (ushort_t)(r >> 16);
}
__device__ inline float bf16_to_f32(ushort_t h) {
  return __uint_as_float(((uint32_t)h) << 16);
}

// async global->LDS, 16B/lane; LDS dest wave-uniform base + lane*16 (linear)
__device__ inline void gload_lds16(const void* g, void* l) {
  __builtin_amdgcn_global_load_lds(
      (const __attribute__((address_space(1))) void*)g,
      (__attribute__((address_space(3))) void*)l,
      16, 0, 0);
}

__device__ inline f32x4 mfma_bf16(short8 a, short8 b, f32x4 c) {
  return __builtin_amdgcn_mfma_f32_16x16x32_bf16(
      __builtin_bit_cast(bf16x8, a), __builtin_bit_cast(bf16x8, b), c, 0, 0, 0);
}

#define BARRIER() asm volatile("s_barrier" ::: "memory")
template <int N> __device__ __forceinline__ void waitvm() {
  if constexpr (N == 8)      asm volatile("s_waitcnt vmcnt(8)" ::: "memory");
  else if constexpr (N == 4) asm volatile("s_waitcnt vmcnt(4)" ::: "memory");
  else                       asm volatile("s_waitcnt vmcnt(0)" ::: "memory");
}

// ------- 1. COO scatter-add directly into bf16 W via u32 CAS loop ----------
// Duplicates sum in bf16 (per-add rounding); ~1ulp on few slots.
__global__ __launch_bounds__(256) void scatter_coo_cas(
    const float* __restrict__ vals, const int* __restrict__ rows,
    const int* __restrict__ cols, uint32_t* __restrict__ W32) {
  int i = blockIdx.x * 256 + threadIdx.x;
  if (i >= NNZ_) return;
  const size_t idx = (size_t)rows[i] * N_IN_ + cols[i];
  const float v = vals[i];
  uint32_t* p = &W32[idx >> 1];
  const bool hi = (idx & 1) != 0;
  uint32_t old = *p, assumed;
  do {
    assumed = old;
    ushort_t h = hi ? (ushort_t)(assumed >> 16) : (ushort_t)(assumed & 0xFFFFu);
    ushort_t nh = f32_to_bf16(bf16_to_f32(h) + v);
    uint32_t nw = hi ? ((assumed & 0x0000FFFFu) | ((uint32_t)nh << 16))
                     : ((assumed & 0xFFFF0000u) | (uint32_t)nh);
    old = atomicCAS(p, assumed, nw);
  } while (old != assumed);
}

// ---------------- 2. inputs [K][N] f32 -> Bt [N][K] bf16 ----------------
__global__ __launch_bounds__(256) void transpose_bf16(
    const float* __restrict__ in, ushort_t* __restrict__ out) {
  __shared__ float tile[32][33];
  const int bx = blockIdx.x * 32, by = blockIdx.y * 32;
  const int tx = threadIdx.x, ty = threadIdx.y;
#pragma unroll
  for (int i = 0; i < 32; i += 8)
    tile[ty + i][tx] = in[(size_t)(by + ty + i) * BATCH_ + bx + tx];
  __syncthreads();
#pragma unroll
  for (int i = 0; i < 32; i += 8)
    out[(size_t)(bx + ty + i) * N_IN_ + by + tx] = f32_to_bf16(tile[tx][ty + i]);
}

// ---------------- 3. 256x256 ring-4 GEMM, 1 barrier per K-tile --------------
// C[m][n] = relu(sum_k A[m][k]*Bt[n][k] + bias[m])
// K-tiles processed in pairs: {vmcnt(4) | B1 | stage t+3 | read+MFMA tile t |
// B2 | stage t+4 | read+MFMA tile t+1}. Counted vmcnt (never 0 in main loop).
// Ring audit: stage t+3 -> buf(t-1), last read drained before B1 (consumed
// pre-B1 MFMAs); stage t+4 -> buf t, read strictly before B2.
#define BM 256
#define BN 256
#define BK 32
#define KTILES 128            // 4096/32
#define TILE_BYTES 32768      // A 16K + B 16K
#define B_OFF 16384

__global__ __launch_bounds__(512, 2) void gemm_bias_relu(
    const ushort_t* __restrict__ A,    // bf16 [N_OUT][N_IN]
    const ushort_t* __restrict__ Bt,   // bf16 [BATCH][N_IN]
    const float* __restrict__ bias,    // [N_OUT]
    float* __restrict__ C) {           // f32 [N_OUT][BATCH]
  __shared__ __align__(16) char smem[4 * TILE_BYTES];  // 128 KiB

  const int tid  = threadIdx.x;
  const int wid  = tid >> 6;
  const int lane = tid & 63;

  // T1: XCD swizzle (nwg=256, 8 XCDs, bijective)
  const int bid = blockIdx.x;
  const int swz = (bid & 7) * 32 + (bid >> 3);
  const int brow = (swz >> 4) * BM;
  const int bcol = (swz & 15) * BN;

  const int wr = wid >> 2;        // 0..1 -> rows wr*128..+128
  const int wc = wid & 3;         // 0..3 -> cols wc*64..+64
  const int fr = lane & 15;
  const int k0slot = lane >> 4;   // 0..3

  // frag LDS byte offsets (T2 XOR swizzle: bits7-8 -> bits4-5, involution)
  int aoff[8], boff[4];
#pragma unroll
  for (int mi = 0; mi < 8; ++mi) {
    int off = (wr * 128 + mi * 16 + fr) * 64 + k0slot * 16;
    aoff[mi] = off ^ (((off >> 7) & 3) << 4);
  }
#pragma unroll
  for (int ni = 0; ni < 4; ++ni) {
    int off = (wc * 64 + ni * 16 + fr) * 64 + k0slot * 16;
    boff[ni] = off ^ (((off >> 7) & 3) << 4);
  }

  // staging: waves 0-3 -> A, 4-7 -> B; wave sw owns 1KB chunks 4sw..4sw+3;
  // pre-swizzled per-lane global source (rule #21)
  const bool isB = wid >= 4;
  const int sw = isB ? wid - 4 : wid;
  const int swzl = lane ^ ((lane >> 3) & 3);
  const int rowInChunk = swzl >> 2;
  const int kelem = (swzl & 3) * 8;
  const ushort_t* gsrc = isB ? Bt : A;
  const size_t laneRowBase =
      (size_t)((isB ? bcol : brow) + sw * 64 + rowInChunk) * N_IN_ + kelem;
  const int ldsOpBase = isB ? B_OFF : 0;

#define STAGE(c, t)                                                           \
  gload_lds16(gsrc + laneRowBase + (size_t)(c) * 16 * N_IN_ + (size_t)(t) * BK,\
              smem + ((t) & 3) * TILE_BYTES + ldsOpBase +                     \
                  (4 * sw + (c)) * 1024)
#define STAGE4(t) do { STAGE(0,(t)); STAGE(1,(t)); STAGE(2,(t)); STAGE(3,(t)); } while (0)

  f32x4 acc[8][4] = {};
  short8 af[8], bf[4];   // shared frag set for both halves of a pair

  // prologue: stage tiles 0,1,2 (12 gloads/wave, oldest-first)
  STAGE4(0); STAGE4(1); STAGE4(2);

// HALF: stage (optional) then read 12 frags + 32 MFMA in one region
#define HALF(t, S_ON, ST)                                                     \
  do {                                                                        \
    const char* buf = &smem[((t) & 3) * TILE_BYTES];                          \
    if (S_ON) STAGE4(ST);                                                     \
    _Pragma("unroll") for (int ni = 0; ni < 4; ++ni)                          \
        bf[ni] = *(const short8*)(buf + B_OFF + boff[ni]);                    \
    _Pragma("unroll") for (int mi = 0; mi < 8; ++mi)                          \
        af[mi] = *(const short8*)(buf + aoff[mi]);                            \
    __builtin_amdgcn_s_setprio(1);                                            \
    _Pragma("unroll") for (int mi = 0; mi < 8; ++mi)                          \
        _Pragma("unroll") for (int ni = 0; ni < 4; ++ni)                      \
            acc[mi][ni] = mfma_bf16(af[mi], bf[ni], acc[mi][ni]);             \
    __builtin_amdgcn_s_setprio(0);                                            \
  } while (0)

#define PAIR(t, S1, S2, VM)                                                   \
  do {                                                                        \
    VM;                                                                       \
    BARRIER();                                                                \
    HALF((t), S1, (t) + 3);                                                   \
    BARRIER();                                                                \
    HALF((t) + 1, S2, (t) + 4);                                               \
  } while (0)

  // main: pairs t=0,2,...,122 full; tail t=124 (stage 127 only), t=126 (none)
  for (int t = 0; t < KTILES - 4; t += 2) PAIR(t, 1, 1, waitvm<4>());
  PAIR(KTILES - 4, 1, 0, waitvm<4>());
  PAIR(KTILES - 2, 0, 0, waitvm<0>());

  // epilogue: C/D map col = lane&15, row = (lane>>4)*4 + reg
  const int r0 = brow + wr * 128 + k0slot * 4;
  const int c0 = bcol + wc * 64 + fr;
#pragma unroll
  for (int mi = 0; mi < 8; ++mi) {
#pragma unroll
    for (int r = 0; r < 4; ++r) {
      const int row = r0 + mi * 16 + r;
      const float b = bias[row];
#pragma unroll
      for (int ni = 0; ni < 4; ++ni) {
        float v = acc[mi][ni][r] + b;
        C[(size_t)row * BATCH_ + c0 + ni * 16] = v > 0.f ? v : 0.f;
      }
    }
  }
#undef PAIR
#undef HALF
#undef STAGE4
#undef STAGE
}

extern "C" void kernel_launch(void* const* d_in, const int* in_sizes, int n_in,
                              void* d_out, int out_size, void* d_ws, size_t ws_size,
                              hipStream_t stream) {
  const float* inputs = (const float*)d_in[0];
  const float* values = (const float*)d_in[1];
  const float* biases = (const float*)d_in[2];
  const int*   rows   = (const int*)d_in[3];
  const int*   cols   = (const int*)d_in[4];
  float* out = (float*)d_out;

  // layout: [0,32M) bf16 W ; [32M,64M) bf16 in^T
  const size_t W_BF16_BYTES = (size_t)N_OUT_ * N_IN_ * 2;  // 32 MiB
  if (ws_size < 2 * W_BF16_BYTES) return;
  char* ws = (char*)d_ws;
  ushort_t* Wb = (ushort_t*)ws;
  ushort_t* Bt = (ushort_t*)(ws + W_BF16_BYTES);

  hipMemsetAsync(Wb, 0, W_BF16_BYTES, stream);
  scatter_coo_cas<<<(NNZ_ + 255) / 256, 256, 0, stream>>>(values, rows, cols,
                                                          (uint32_t*)Wb);
  transpose_bf16<<<dim3(BATCH_ / 32, N_IN_ / 32), dim3(32, 8), 0, stream>>>(inputs, Bt);
  gemm_bias_relu<<<dim3(256), 512, 0, stream>>>(Wb, Bt, biases, out);
}

// Round 8
// 208.100 us; speedup vs baseline: 1.3216x; 1.0122x over previous
//
#include <hip/hip_runtime.h>
#include <stdint.h>

#define N_OUT_  4096
#define N_IN_   4096
#define BATCH_  4096
#define NNZ_    1600000

typedef unsigned short ushort_t;
typedef float  f32x4  __attribute__((ext_vector_type(4)));
typedef short  short8 __attribute__((ext_vector_type(8)));
typedef __bf16 bf16x8 __attribute__((ext_vector_type(8)));

// RNE f32 -> bf16
__device__ inline ushort_t f32_to_bf16(float f) {
  uint32_t u = __float_as_uint(f);
  uint32_t r = u + 0x7FFFu + ((u >> 16) & 1u);
  return (ushort_t)(r >> 16);
}
__device__ inline float bf16_to_f32(ushort_t h) {
  return __uint_as_float(((uint32_t)h) << 16);
}

// async global->LDS, 16B/lane; LDS dest wave-uniform base + lane*16 (linear)
__device__ inline void gload_lds16(const void* g, void* l) {
  __builtin_amdgcn_global_load_lds(
      (const __attribute__((address_space(1))) void*)g,
      (__attribute__((address_space(3))) void*)l,
      16, 0, 0);
}

__device__ inline f32x4 mfma_bf16(short8 a, short8 b, f32x4 c) {
  return __builtin_amdgcn_mfma_f32_16x16x32_bf16(
      __builtin_bit_cast(bf16x8, a), __builtin_bit_cast(bf16x8, b), c, 0, 0, 0);
}

#define BARRIER() asm volatile("s_barrier" ::: "memory")
template <int N> __device__ __forceinline__ void waitvm() {
  if constexpr (N == 4)      asm volatile("s_waitcnt vmcnt(4)" ::: "memory");
  else                       asm volatile("s_waitcnt vmcnt(0)" ::: "memory");
}

// ------- 1. COO scatter-add directly into bf16 W via u32 CAS loop ----------
__global__ __launch_bounds__(256) void scatter_coo_cas(
    const float* __restrict__ vals, const int* __restrict__ rows,
    const int* __restrict__ cols, uint32_t* __restrict__ W32) {
  int i = blockIdx.x * 256 + threadIdx.x;
  if (i >= NNZ_) return;
  const size_t idx = (size_t)rows[i] * N_IN_ + cols[i];
  const float v = vals[i];
  uint32_t* p = &W32[idx >> 1];
  const bool hi = (idx & 1) != 0;
  uint32_t old = *p, assumed;
  do {
    assumed = old;
    ushort_t h = hi ? (ushort_t)(assumed >> 16) : (ushort_t)(assumed & 0xFFFFu);
    ushort_t nh = f32_to_bf16(bf16_to_f32(h) + v);
    uint32_t nw = hi ? ((assumed & 0x0000FFFFu) | ((uint32_t)nh << 16))
                     : ((assumed & 0xFFFF0000u) | (uint32_t)nh);
    old = atomicCAS(p, assumed, nw);
  } while (old != assumed);
}

// ------- 2. fused: memset Wb (blocks >= 16384) + transpose inputs ----------
#define TR_BLOCKS 16384   // (4096/32)^2
#define MS_BLOCKS 2048    // 2M uint4 = 32 MiB zeroed, 4 uint4/thread
__global__ __launch_bounds__(256) void prep_fused(
    const float* __restrict__ in, ushort_t* __restrict__ out,
    uint4* __restrict__ Wb4) {
  const int b = blockIdx.x;
  if (b < TR_BLOCKS) {
    __shared__ float tile[32][33];
    const int bx = (b & 127) * 32, by = (b >> 7) * 32;
    const int tx = threadIdx.x & 31, ty = threadIdx.x >> 5;
#pragma unroll
    for (int i = 0; i < 32; i += 8)
      tile[ty + i][tx] = in[(size_t)(by + ty + i) * BATCH_ + bx + tx];
    __syncthreads();
#pragma unroll
    for (int i = 0; i < 32; i += 8)
      out[(size_t)(bx + ty + i) * N_IN_ + by + tx] = f32_to_bf16(tile[tx][ty + i]);
  } else {
    const uint4 z = {0u, 0u, 0u, 0u};
    const int idx = (b - TR_BLOCKS) * 256 + threadIdx.x;
#pragma unroll
    for (int j = 0; j < 4; ++j) Wb4[idx + j * (MS_BLOCKS * 256)] = z;
  }
}

// ---------------- 3. 256x256 ring-4 GEMM, 1 barrier/tile + read-ahead -------
// C[m][n] = relu(sum_k A[m][k]*Bt[n][k] + bias[m])
// TILE(t): stage4(t+3) | RA: read 12 frags of tile t+1 into alt reg set |
//          32 MFMA on cur set | vmcnt(4) | barrier.
// Visibility: buf t+1 retired by vmcnt at end of t-1 + barrier. Ring WAR:
// stage t+3 -> buf(t-1), RA reads of it (issued t-2) drained before their
// consuming MFMAs in t-1, before end-of-(t-1) barrier.
#define BM 256
#define BN 256
#define BK 32
#define KTILES 128            // 4096/32
#define TILE_BYTES 32768      // A 16K + B 16K
#define B_OFF 16384

__global__ __launch_bounds__(512, 2) void gemm_bias_relu(
    const ushort_t* __restrict__ A,    // bf16 [N_OUT][N_IN]
    const ushort_t* __restrict__ Bt,   // bf16 [BATCH][N_IN]
    const float* __restrict__ bias,    // [N_OUT]
    float* __restrict__ C) {           // f32 [N_OUT][BATCH]
  __shared__ __align__(16) char smem[4 * TILE_BYTES];  // 128 KiB

  const int tid  = threadIdx.x;
  const int wid  = tid >> 6;
  const int lane = tid & 63;

  // T1: XCD swizzle (nwg=256, 8 XCDs, bijective)
  const int bid = blockIdx.x;
  const int swz = (bid & 7) * 32 + (bid >> 3);
  const int brow = (swz >> 4) * BM;
  const int bcol = (swz & 15) * BN;

  const int wr = wid >> 2;        // 0..1 -> rows wr*128..+128
  const int wc = wid & 3;         // 0..3 -> cols wc*64..+64
  const int fr = lane & 15;
  const int k0slot = lane >> 4;   // 0..3

  // frag LDS byte offsets (T2 XOR swizzle: bits7-8 -> bits4-5; the XOR term
  // depends only on fr, so aoff[mi] = aoff[0] + mi*1024 -> base+imm in asm)
  int aoff[8], boff[4];
#pragma unroll
  for (int mi = 0; mi < 8; ++mi) {
    int off = (wr * 128 + mi * 16 + fr) * 64 + k0slot * 16;
    aoff[mi] = off ^ (((off >> 7) & 3) << 4);
  }
#pragma unroll
  for (int ni = 0; ni < 4; ++ni) {
    int off = (wc * 64 + ni * 16 + fr) * 64 + k0slot * 16;
    boff[ni] = off ^ (((off >> 7) & 3) << 4);
  }

  // staging: waves 0-3 -> A, 4-7 -> B; wave sw owns 1KB chunks 4sw..4sw+3;
  // pre-swizzled per-lane global source (rule #21)
  const bool isB = wid >= 4;
  const int sw = isB ? wid - 4 : wid;
  const int swzl = lane ^ ((lane >> 3) & 3);
  const int rowInChunk = swzl >> 2;
  const int kelem = (swzl & 3) * 8;
  const ushort_t* gsrc = isB ? Bt : A;
  const size_t laneRowBase =
      (size_t)((isB ? bcol : brow) + sw * 64 + rowInChunk) * N_IN_ + kelem;
  const int ldsOpBase = isB ? B_OFF : 0;

#define STAGE(c, t)                                                           \
  gload_lds16(gsrc + laneRowBase + (size_t)(c) * 16 * N_IN_ + (size_t)(t) * BK,\
              smem + ((t) & 3) * TILE_BYTES + ldsOpBase +                     \
                  (4 * sw + (c)) * 1024)
#define STAGE4(t) do { STAGE(0,(t)); STAGE(1,(t)); STAGE(2,(t)); STAGE(3,(t)); } while (0)

  f32x4 acc[8][4] = {};
  short8 aX[8], bX[4], aY[8], bY[4];   // ping-pong frag sets

#define RDSET(NA, NB, bufp)                                                   \
  do {                                                                        \
    _Pragma("unroll") for (int ni = 0; ni < 4; ++ni)                          \
        NB[ni] = *(const short8*)((bufp) + B_OFF + boff[ni]);                 \
    _Pragma("unroll") for (int mi = 0; mi < 8; ++mi)                          \
        NA[mi] = *(const short8*)((bufp) + aoff[mi]);                         \
  } while (0)

#define MFMAC(CA, CB)                                                         \
  do {                                                                        \
    __builtin_amdgcn_s_setprio(1);                                            \
    _Pragma("unroll") for (int mi = 0; mi < 8; ++mi)                          \
        _Pragma("unroll") for (int ni = 0; ni < 4; ++ni)                      \
            acc[mi][ni] = mfma_bf16(CA[mi], CB[ni], acc[mi][ni]);             \
    __builtin_amdgcn_s_setprio(0);                                            \
  } while (0)

// TILE: stage | RA next-set | MFMA cur-set | wait | (barrier by caller)
#define TILE(t, CA, CB, NA, NB, S_ON, RA_ON, VM)                              \
  do {                                                                        \
    const char* bufn = &smem[(((t) + 1) & 3) * TILE_BYTES];                   \
    if (S_ON) STAGE4((t) + 3);                                                \
    if (RA_ON) RDSET(NA, NB, bufn);                                           \
    MFMAC(CA, CB);                                                            \
    VM;                                                                       \
  } while (0)

  // prologue: stage 0,1,2; vmcnt(4) retires 0,1; barrier; preload X <- buf 0
  STAGE4(0); STAGE4(1); STAGE4(2);
  waitvm<4>();
  BARRIER();
  RDSET(aX, bX, smem);

  // main: tiles 0..123 (stage t+3 <= 126), 1 barrier per tile
  for (int t = 0; t < KTILES - 4; t += 2) {
    TILE(t,     aX, bX, aY, bY, 1, 1, waitvm<4>());
    BARRIER();
    TILE(t + 1, aY, bY, aX, bX, 1, 1, waitvm<4>());
    BARRIER();
  }
  TILE(KTILES - 4, aX, bX, aY, bY, 1, 1, waitvm<4>());  // stages 127
  BARRIER();
  TILE(KTILES - 3, aY, bY, aX, bX, 0, 1, waitvm<0>());  // retires 127
  BARRIER();
  TILE(KTILES - 2, aX, bX, aY, bY, 0, 1, (void)0);      // RA buf 127
  TILE(KTILES - 1, aY, bY, aX, bX, 0, 0, (void)0);

  // epilogue: C/D map col = lane&15, row = (lane>>4)*4 + reg
  const int r0 = brow + wr * 128 + k0slot * 4;
  const int c0 = bcol + wc * 64 + fr;
#pragma unroll
  for (int mi = 0; mi < 8; ++mi) {
#pragma unroll
    for (int r = 0; r < 4; ++r) {
      const int row = r0 + mi * 16 + r;
      const float b = bias[row];
#pragma unroll
      for (int ni = 0; ni < 4; ++ni) {
        float v = acc[mi][ni][r] + b;
        C[(size_t)row * BATCH_ + c0 + ni * 16] = v > 0.f ? v : 0.f;
      }
    }
  }
#undef TILE
#undef MFMAC
#undef RDSET
#undef STAGE4
#undef STAGE
}

extern "C" void kernel_launch(void* const* d_in, const int* in_sizes, int n_in,
                              void* d_out, int out_size, void* d_ws, size_t ws_size,
                              hipStream_t stream) {
  const float* inputs = (const float*)d_in[0];
  const float* values = (const float*)d_in[1];
  const float* biases = (const float*)d_in[2];
  const int*   rows   = (const int*)d_in[3];
  const int*   cols   = (const int*)d_in[4];
  float* out = (float*)d_out;

  // layout: [0,32M) bf16 W ; [32M,64M) bf16 in^T
  const size_t W_BF16_BYTES = (size_t)N_OUT_ * N_IN_ * 2;  // 32 MiB
  if (ws_size < 2 * W_BF16_BYTES) return;
  char* ws = (char*)d_ws;
  ushort_t* Wb = (ushort_t*)ws;
  ushort_t* Bt = (ushort_t*)(ws + W_BF16_BYTES);

  prep_fused<<<TR_BLOCKS + MS_BLOCKS, 256, 0, stream>>>(inputs, Bt, (uint4*)Wb);
  scatter_coo_cas<<<(NNZ_ + 255) / 256, 256, 0, stream>>>(values, rows, cols,
                                                          (uint32_t*)Wb);
  gemm_bias_relu<<<dim3(256), 512, 0, stream>>>(Wb, Bt, biases, out);
}